// Round 17
// baseline (1440.543 us; speedup 1.0000x reference)
//
#include <hip/hip_runtime.h>

#define SEQ 2048
#define HEADS 16
#define DEPTH 64
#define DIMS 1024
#define LOG2E 1.44269504088896340736f
#define NT128 16               // 2048 keys / 128-key tiles

typedef _Float16 f16x8 __attribute__((ext_vector_type(8)));
typedef __fp16 fp16v2 __attribute__((ext_vector_type(2)));
typedef float f32x16 __attribute__((ext_vector_type(16)));

__device__ __forceinline__ f32x16 mfma32(f16x8 a, f16x8 b, f32x16 c) {
  return __builtin_amdgcn_mfma_f32_32x32x16_f16(a, b, c, 0, 0, 0);
}

#if __has_builtin(__builtin_amdgcn_exp2f)
#define EXP2(x) __builtin_amdgcn_exp2f(x)
#else
#define EXP2(x) exp2f(x)
#endif

__device__ __forceinline__ unsigned pkbits(float a, float b) {
  union { fp16v2 h; unsigned u; } cv;
  cv.h = __builtin_amdgcn_cvt_pkrtz(a, b);
  return cv.u;
}

// direct global->LDS DMA, 16B/lane; LDS dest = wave-uniform base + lane*16
#define GLOAD_LDS(g, l)                                                        \
  __builtin_amdgcn_global_load_lds(                                            \
      (const __attribute__((address_space(1))) unsigned int*)(g),              \
      (__attribute__((address_space(3))) unsigned int*)(l), 16, 0, 0)

// ---------- fused prepass: K -> fp16 [bh][S][D];  V -> fp16 [bh][D][S] ------
__global__ __launch_bounds__(256) void prep_kv(const float* __restrict__ k,
                                               const float* __restrict__ v,
                                               _Float16* __restrict__ khf,
                                               _Float16* __restrict__ vtp) {
  const int bid = blockIdx.x;
  if (bid < 2048) {              // ---- K half: one thread per 8 elems ----
    int t = bid * 256 + threadIdx.x;
    size_t flat = (size_t)t * 8;
    int b = (int)(flat >> 21);                    // S*DIMS = 2^21
    int rem = (int)(flat & ((1u << 21) - 1));
    int s = rem >> 10;
    int c = rem & 1023;
    int h = c >> 6;
    int d = c & 63;
    float4 a0 = *(const float4*)(k + flat);
    float4 a1 = *(const float4*)(k + flat + 4);
    float f[8] = {a0.x, a0.y, a0.z, a0.w, a1.x, a1.y, a1.z, a1.w};
    f16x8 th;
    #pragma unroll
    for (int j = 0; j < 8; ++j) th[j] = (_Float16)f[j];
    size_t o = ((size_t)(b * HEADS + h) * SEQ + s) * DEPTH + d;
    *(f16x8*)(khf + o) = th;
  } else {                       // ---- V half: transpose to [bh][D][S] ----
    int t = (bid - 2048) * 256 + threadIdx.x;
    int d = t & 63;
    int sg = (t >> 6) & 255;
    int bh = t >> 14;
    int b = bh >> 4, h = bh & 15;
    int s0 = sg * 8;
    const float* src = v + ((size_t)(b * SEQ + s0)) * DIMS + h * DEPTH + d;
    _Float16* dst = vtp + ((size_t)bh * DEPTH + d) * SEQ + s0;
    f16x8 tv;
    #pragma unroll
    for (int i = 0; i < 8; ++i) tv[i] = (_Float16)src[(size_t)i * DIMS];
    *(f16x8*)dst = tv;
  }
}

// ---------- main: flash attention, 128-key tiles, 32x32x16 MFMA ----------
// r15 structure + chunk-level online softmax: scores processed in 32-key
// chunks so qkt(k+1)'s MFMAs are issued BEFORE softmax(k)'s VALU (explicit
// order, named chunk registers). Swizzle: 16B data chunk c of row r at LDS
// chunk c ^ ((r&7)^((r>>3)&3)). P in registers (cvt_pk + permlane32_swap);
// den via ones-MFMA in C-layout (A/B-proven vs VALU den in r15/r16).
__global__ __launch_bounds__(256, 2) void attn_fwd(
    const float* __restrict__ q, const _Float16* __restrict__ kh,
    const _Float16* __restrict__ vt, float* __restrict__ out) {
  __shared__ _Float16 Kl[2][128 * 64];
  __shared__ _Float16 Vl[2][64 * 128];

  const int tid = threadIdx.x;
  const int w = tid >> 6;
  const int l = tid & 63;
  const int q32 = l & 31;        // lane's q-row (and V d-row) index
  const int hi = l >> 5;

  // XCD-chunked bijective swizzle: 512 blocks = 8 XCDs x 64.
  const int bid = blockIdx.x;
  const int wg = (bid & 7) * 64 + (bid >> 3);
  const int qt = wg & 15;        // q-tile of 128 rows
  const int bh = wg >> 4;        // 0..31
  const int b = bh >> 4;
  const int h = bh & 15;

  const int qb = qt * 128 + w * 32;      // wave's first q row (32 rows/wave)
  const int hoff = h * DEPTH;
  const size_t kvoff = (size_t)bh * SEQ * DEPTH;

  // ---- Q B-fragments (n = q = q32, k-step c: dims c*16 + 8*hi + j), *log2e
  f16x8 qf[4];
  {
    const float* gq = q + (size_t)(b * SEQ + qb + q32) * DIMS + hoff + 8 * hi;
    #pragma unroll
    for (int c = 0; c < 4; ++c) {
      float4 a0 = *(const float4*)(gq + 16 * c);
      float4 a1 = *(const float4*)(gq + 16 * c + 4);
      float f[8] = {a0.x, a0.y, a0.z, a0.w, a1.x, a1.y, a1.z, a1.w};
      f16x8 t;
      #pragma unroll
      for (int j = 0; j < 8; ++j) t[j] = (_Float16)(f[j] * LOG2E);
      qf[c] = t;
    }
  }

  // ---- staging sources (per-lane pre-swizzle) ----
  const _Float16* gkp[4];
  const _Float16* gvp[4];
  #pragma unroll
  for (int i = 0; i < 4; ++i) {
    const int krow = 32 * w + 8 * i + (l >> 3);
    gkp[i] = kh + kvoff + (size_t)krow * DEPTH +
             (((l & 7) ^ (l >> 3) ^ ((4 * w + i) & 3)) * 8);
    const int vrow = 16 * w + 4 * i + (l >> 4);
    const int vmask = (vrow & 7) ^ ((vrow >> 3) & 3);
    gvp[i] = vt + kvoff + (size_t)vrow * SEQ + (((l & 15) ^ vmask) * 8);
  }

  // fragment-read chunk offsets (mask0 shared by all rows actually read)
  const int mask0 = (q32 & 7) ^ ((q32 >> 3) & 3);
  int kco[4], vco[8];
  #pragma unroll
  for (int c = 0; c < 4; ++c) kco[c] = ((2 * c + hi) ^ mask0) * 8;
  #pragma unroll
  for (int s = 0; s < 8; ++s) vco[s] = ((2 * s + hi) ^ mask0) * 8;

  f32x16 acc0 = {}, acc1 = {};   // O: col d = q32 (+32), row q = crow(r,hi)
  f32x16 dacc = {};              // denominator, same C rows (cols replicated)
  float mrow = -3e38f;           // running max (log2 domain) for q-row q32

  const f16x8 onesf = {1, 1, 1, 1, 1, 1, 1, 1};

  auto stage = [&](int buf, int t) {
    #pragma unroll
    for (int i = 0; i < 4; ++i)
      GLOAD_LDS(gkp[i] + (size_t)t * 128 * DEPTH,
                &Kl[buf][(32 * w + 8 * i) * 64]);
    #pragma unroll
    for (int i = 0; i < 4; ++i)
      GLOAD_LDS(gvp[i] + t * 128, &Vl[buf][(16 * w + 4 * i) * 128]);
  };

  // QK^T for a 32-key chunk k: scores for keys 32k + crow(r,hi); q = q32
  auto qkt_chunk = [&](int buf, int k) -> f32x16 {
    f32x16 s = {};
    __builtin_amdgcn_s_setprio(1);
    #pragma unroll
    for (int c = 0; c < 4; ++c) {
      f16x8 kf = *(const f16x8*)&Kl[buf][(32 * k + q32) * 64 + kco[c]];
      s = mfma32(kf, qf[c], s);
    }
    __builtin_amdgcn_s_setprio(0);
    return s;
  };

  // online softmax + pack + PV for chunk k (keys 32k..32k+31)
  auto smax_pv = [&](int buf, int k, f32x16& st) {
    float mx = fmaxf(st[0], st[1]);
    #pragma unroll
    for (int r = 2; r < 16; r += 2) mx = fmaxf(mx, fmaxf(st[r], st[r + 1]));
    if (!__all(mx - mrow <= 8.0f)) {       // defer-max THR=8
      mx = fmaxf(mx, __shfl_xor(mx, 32));
      float mnew = fmaxf(mrow, mx);
      float sc = EXP2(mrow - mnew);
      mrow = mnew;
      #pragma unroll
      for (int r = 0; r < 16; ++r) {
        const int crow = (r & 3) + 8 * (r >> 2) + 4 * hi;
        float scb = __shfl(sc, crow);
        acc0[r] *= scb;
        acc1[r] *= scb;
        dacc[r] *= scb;
      }
    }
    #pragma unroll
    for (int r = 0; r < 16; ++r) st[r] = EXP2(st[r] - mrow);

    // P -> PV A-fragments in-register (cvt_pk + permlane32_swap)
    f16x8 pa0, pa1;
    {
      unsigned x0 = pkbits(st[0], st[1]);
      unsigned x1 = pkbits(st[2], st[3]);
      unsigned y0 = pkbits(st[4], st[5]);
      unsigned y1 = pkbits(st[6], st[7]);
      asm("v_permlane32_swap_b32 %0, %1" : "+v"(x0), "+v"(y0));
      asm("v_permlane32_swap_b32 %0, %1" : "+v"(x1), "+v"(y1));
      union { unsigned u[4]; f16x8 v; } pu;
      pu.u[0] = x0; pu.u[1] = x1; pu.u[2] = y0; pu.u[3] = y1;
      pa0 = pu.v;
      unsigned z0 = pkbits(st[8], st[9]);
      unsigned z1 = pkbits(st[10], st[11]);
      unsigned t0 = pkbits(st[12], st[13]);
      unsigned t1 = pkbits(st[14], st[15]);
      asm("v_permlane32_swap_b32 %0, %1" : "+v"(z0), "+v"(t0));
      asm("v_permlane32_swap_b32 %0, %1" : "+v"(z1), "+v"(t1));
      union { unsigned u[4]; f16x8 v; } pv;
      pv.u[0] = z0; pv.u[1] = z1; pv.u[2] = t0; pv.u[3] = t1;
      pa1 = pv.v;
    }

    // PV + den for this chunk (V^T columns 32k..32k+31)
    __builtin_amdgcn_s_setprio(1);
    {
      f16x8 vf0 = *(const f16x8*)&Vl[buf][q32 * 128 + vco[2 * k]];
      f16x8 vf1 = *(const f16x8*)&Vl[buf][(32 + q32) * 128 + vco[2 * k]];
      acc0 = mfma32(pa0, vf0, acc0);
      acc1 = mfma32(pa0, vf1, acc1);
      dacc = mfma32(pa0, onesf, dacc);
      f16x8 vf2 = *(const f16x8*)&Vl[buf][q32 * 128 + vco[2 * k + 1]];
      f16x8 vf3 = *(const f16x8*)&Vl[buf][(32 + q32) * 128 + vco[2 * k + 1]];
      acc0 = mfma32(pa1, vf2, acc0);
      acc1 = mfma32(pa1, vf3, acc1);
      dacc = mfma32(pa1, onesf, dacc);
    }
    __builtin_amdgcn_s_setprio(0);
  };

  // compute: chunk-pipelined -- qkt(k+1) issued before softmax/PV(k)
  auto compute = [&](int buf) {
    f32x16 s0 = qkt_chunk(buf, 0);
    f32x16 s1 = qkt_chunk(buf, 1);
    smax_pv(buf, 0, s0);
    f32x16 s2 = qkt_chunk(buf, 2);
    smax_pv(buf, 1, s1);
    f32x16 s3 = qkt_chunk(buf, 3);
    smax_pv(buf, 2, s2);
    smax_pv(buf, 3, s3);
  };

  // ---- 2-phase pipeline: stage t+1 early, ONE barrier per 128-key tile ----
  stage(0, 0);
  __syncthreads();                      // drains vmcnt -> tile 0 visible
  #pragma unroll 1
  for (int t = 0; t < NT128; t += 2) {
    stage(1, t + 1);                    // in flight during compute
    compute(0);
    __syncthreads();                    // drain + WAR fence
    if (t + 2 < NT128) stage(0, t + 2);
    compute(1);
    __syncthreads();
  }

  // ---- epilogue: den in C-layout (cols replicated) -> shfl-free ----
  #pragma unroll
  for (int r = 0; r < 16; ++r) {
    const int crow = (r & 3) + 8 * (r >> 2) + 4 * hi;
    float rden = 1.0f / dacc[r];
    float* po = out + (size_t)(b * SEQ + qb + crow) * DIMS + hoff;
    po[q32] = acc0[r] * rden;
    po[32 + q32] = acc1[r] * rden;
  }
}

extern "C" void kernel_launch(void* const* d_in, const int* in_sizes, int n_in,
                              void* d_out, int out_size, void* d_ws, size_t ws_size,
                              hipStream_t stream) {
  const float* q = (const float*)d_in[0];
  const float* k = (const float*)d_in[1];
  const float* v = (const float*)d_in[2];
  float* out = (float*)d_out;

  // workspace: Khf | Vt, each 2*16*2048*64 fp16 = 8 MiB
  const size_t tsz = (size_t)2 * HEADS * SEQ * DEPTH;  // elements
  _Float16* khf = (_Float16*)d_ws;
  _Float16* vtp = khf + tsz;

  prep_kv<<<4096, 256, 0, stream>>>(k, v, khf, vtp);
  attn_fwd<<<512, 256, 0, stream>>>(q, khf, vtp, out);
}

// Round 18
// 67.297 us; speedup vs baseline: 21.4057x; 21.4057x over previous
//
#include <hip/hip_runtime.h>

#define SEQ 2048
#define HEADS 16
#define DEPTH 64
#define DIMS 1024
#define LOG2E 1.44269504088896340736f
#define NT128 16               // 2048 keys / 128-key tiles

typedef _Float16 f16x8 __attribute__((ext_vector_type(8)));
typedef __fp16 fp16v2 __attribute__((ext_vector_type(2)));
typedef float f32x16 __attribute__((ext_vector_type(16)));

__device__ __forceinline__ f32x16 mfma32(f16x8 a, f16x8 b, f32x16 c) {
  return __builtin_amdgcn_mfma_f32_32x32x16_f16(a, b, c, 0, 0, 0);
}

#if __has_builtin(__builtin_amdgcn_exp2f)
#define EXP2(x) __builtin_amdgcn_exp2f(x)
#else
#define EXP2(x) exp2f(x)
#endif

__device__ __forceinline__ unsigned pkbits(float a, float b) {
  union { fp16v2 h; unsigned u; } cv;
  cv.h = __builtin_amdgcn_cvt_pkrtz(a, b);
  return cv.u;
}

// direct global->LDS DMA, 16B/lane; LDS dest = wave-uniform base + lane*16
#define GLOAD_LDS(g, l)                                                        \
  __builtin_amdgcn_global_load_lds(                                            \
      (const __attribute__((address_space(1))) unsigned int*)(g),              \
      (__attribute__((address_space(3))) unsigned int*)(l), 16, 0, 0)

// ---------- fused prepass: K -> fp16 [bh][S][D];  V -> fp16 [bh][D][S] ------
__global__ __launch_bounds__(256) void prep_kv(const float* __restrict__ k,
                                               const float* __restrict__ v,
                                               _Float16* __restrict__ khf,
                                               _Float16* __restrict__ vtp) {
  const int bid = blockIdx.x;
  if (bid < 2048) {              // ---- K half: one thread per 8 elems ----
    int t = bid * 256 + threadIdx.x;
    size_t flat = (size_t)t * 8;
    int b = (int)(flat >> 21);                    // S*DIMS = 2^21
    int rem = (int)(flat & ((1u << 21) - 1));
    int s = rem >> 10;
    int c = rem & 1023;
    int h = c >> 6;
    int d = c & 63;
    float4 a0 = *(const float4*)(k + flat);
    float4 a1 = *(const float4*)(k + flat + 4);
    float f[8] = {a0.x, a0.y, a0.z, a0.w, a1.x, a1.y, a1.z, a1.w};
    f16x8 th;
    #pragma unroll
    for (int j = 0; j < 8; ++j) th[j] = (_Float16)f[j];
    size_t o = ((size_t)(b * HEADS + h) * SEQ + s) * DEPTH + d;
    *(f16x8*)(khf + o) = th;
  } else {                       // ---- V half: transpose to [bh][D][S] ----
    int t = (bid - 2048) * 256 + threadIdx.x;
    int d = t & 63;
    int sg = (t >> 6) & 255;
    int bh = t >> 14;
    int b = bh >> 4, h = bh & 15;
    int s0 = sg * 8;
    const float* src = v + ((size_t)(b * SEQ + s0)) * DIMS + h * DEPTH + d;
    _Float16* dst = vtp + ((size_t)bh * DEPTH + d) * SEQ + s0;
    f16x8 tv;
    #pragma unroll
    for (int i = 0; i < 8; ++i) tv[i] = (_Float16)src[(size_t)i * DIMS];
    *(f16x8*)dst = tv;
  }
}

// ---------- main: flash attention, 128-key tiles, 32x32x16 MFMA ----------
// K tile [128][64] fp16 (128B rows), V^T tile [64][128] (256B rows), both
// double-buffered (64KB LDS). Swizzle: 16B data chunk c of row r lives at
// LDS chunk c ^ mask(r), mask(r) = (r&7)^((r>>3)&3). P in registers
// (cvt_pk + permlane32_swap); den via ones-MFMA in C-layout. One barrier
// per 128 keys. [Round-15 configuration — session best, 67.4 us total.]
__global__ __launch_bounds__(256, 2) void attn_fwd(
    const float* __restrict__ q, const _Float16* __restrict__ kh,
    const _Float16* __restrict__ vt, float* __restrict__ out) {
  __shared__ _Float16 Kl[2][128 * 64];
  __shared__ _Float16 Vl[2][64 * 128];

  const int tid = threadIdx.x;
  const int w = tid >> 6;
  const int l = tid & 63;
  const int q32 = l & 31;        // lane's q-row (and V d-row) index
  const int hi = l >> 5;

  // XCD-chunked bijective swizzle: 512 blocks = 8 XCDs x 64; consecutive
  // wgs on one XCD share (b,h) -> K/V panel stays in that XCD's L2.
  const int bid = blockIdx.x;
  const int wg = (bid & 7) * 64 + (bid >> 3);
  const int qt = wg & 15;        // q-tile of 128 rows
  const int bh = wg >> 4;        // 0..31
  const int b = bh >> 4;
  const int h = bh & 15;

  const int qb = qt * 128 + w * 32;      // wave's first q row (32 rows/wave)
  const int hoff = h * DEPTH;
  const size_t kvoff = (size_t)bh * SEQ * DEPTH;

  // ---- Q B-fragments (n = q = q32, k-step c: dims c*16 + 8*hi + j), *log2e
  f16x8 qf[4];
  {
    const float* gq = q + (size_t)(b * SEQ + qb + q32) * DIMS + hoff + 8 * hi;
    #pragma unroll
    for (int c = 0; c < 4; ++c) {
      float4 a0 = *(const float4*)(gq + 16 * c);
      float4 a1 = *(const float4*)(gq + 16 * c + 4);
      float f[8] = {a0.x, a0.y, a0.z, a0.w, a1.x, a1.y, a1.z, a1.w};
      f16x8 t;
      #pragma unroll
      for (int j = 0; j < 8; ++j) t[j] = (_Float16)(f[j] * LOG2E);
      qf[c] = t;
    }
  }

  // ---- staging sources (per-lane pre-swizzle) ----
  // K gload i (i=0..3): rows 32w+8i..+7; lane -> row +(l>>3), LDS chunk l&7
  //   data chunk = (l&7) ^ (l>>3) ^ ((4w+i)&3)   [mask of row 32w+8i+(l>>3)]
  // V gload i: d-rows 16w+4i..+3; lane -> row +(l>>4), LDS chunk l&15
  //   data chunk = (l&15) ^ vmask(row)
  const _Float16* gkp[4];
  const _Float16* gvp[4];
  #pragma unroll
  for (int i = 0; i < 4; ++i) {
    const int krow = 32 * w + 8 * i + (l >> 3);
    gkp[i] = kh + kvoff + (size_t)krow * DEPTH +
             (((l & 7) ^ (l >> 3) ^ ((4 * w + i) & 3)) * 8);
    const int vrow = 16 * w + 4 * i + (l >> 4);
    const int vmask = (vrow & 7) ^ ((vrow >> 3) & 3);
    gvp[i] = vt + kvoff + (size_t)vrow * SEQ + (((l & 15) ^ vmask) * 8);
  }

  // fragment-read chunk offsets (mask0 shared by all rows actually read)
  const int mask0 = (q32 & 7) ^ ((q32 >> 3) & 3);
  int kco[4], vco[8];
  #pragma unroll
  for (int c = 0; c < 4; ++c) kco[c] = ((2 * c + hi) ^ mask0) * 8;
  #pragma unroll
  for (int s = 0; s < 8; ++s) vco[s] = ((2 * s + hi) ^ mask0) * 8;

  f32x16 acc0 = {}, acc1 = {};   // O: col d = q32 (+32), row q = crow(r,hi)
  f32x16 dacc = {};              // denominator, same C rows (cols replicated)
  float mrow = -3e38f;           // running max (log2 domain) for q-row q32

  const f16x8 onesf = {1, 1, 1, 1, 1, 1, 1, 1};

  auto stage = [&](int buf, int t) {
    #pragma unroll
    for (int i = 0; i < 4; ++i)
      GLOAD_LDS(gkp[i] + (size_t)t * 128 * DEPTH,
                &Kl[buf][(32 * w + 8 * i) * 64]);
    #pragma unroll
    for (int i = 0; i < 4; ++i)
      GLOAD_LDS(gvp[i] + t * 128, &Vl[buf][(16 * w + 4 * i) * 128]);
  };

  auto compute = [&](int buf) {
    // ---- QK^T swapped: st[k] = scores for keys 32k+crow; q = q32 ----
    f32x16 st[4];
    __builtin_amdgcn_s_setprio(1);
    #pragma unroll
    for (int k = 0; k < 4; ++k) {
      f32x16 z = {};
      st[k] = z;
      #pragma unroll
      for (int c = 0; c < 4; ++c) {
        f16x8 kf = *(const f16x8*)&Kl[buf][(32 * k + q32) * 64 + kco[c]];
        st[k] = mfma32(kf, qf[c], st[k]);
      }
    }
    __builtin_amdgcn_s_setprio(0);

    // ---- online softmax: 128 scores of q-row q32 split across hi pair ----
    float mx = fmaxf(st[0][0], st[0][1]);
    #pragma unroll
    for (int k = 0; k < 4; ++k)
      #pragma unroll
      for (int r = (k == 0 ? 2 : 0); r < 16; r += 2)
        mx = fmaxf(mx, fmaxf(st[k][r], st[k][r + 1]));   // v_max3 chains
    if (!__all(mx - mrow <= 8.0f)) {       // defer-max THR=8
      mx = fmaxf(mx, __shfl_xor(mx, 32));
      float mnew = fmaxf(mrow, mx);
      float sc = EXP2(mrow - mnew);
      mrow = mnew;
      #pragma unroll
      for (int r = 0; r < 16; ++r) {
        const int crow = (r & 3) + 8 * (r >> 2) + 4 * hi;
        float scb = __shfl(sc, crow);
        acc0[r] *= scb;
        acc1[r] *= scb;
        dacc[r] *= scb;
      }
    }
    #pragma unroll
    for (int k = 0; k < 4; ++k)
      #pragma unroll
      for (int r = 0; r < 16; ++r) st[k][r] = EXP2(st[k][r] - mrow);

    // ---- P -> PV A-fragments in-register (cvt_pk + permlane32_swap) ----
    f16x8 pa[8];
    #pragma unroll
    for (int k = 0; k < 4; ++k) {
      #pragma unroll
      for (int sl = 0; sl < 2; ++sl) {
        unsigned x0 = pkbits(st[k][8 * sl + 0], st[k][8 * sl + 1]);
        unsigned x1 = pkbits(st[k][8 * sl + 2], st[k][8 * sl + 3]);
        unsigned y0 = pkbits(st[k][8 * sl + 4], st[k][8 * sl + 5]);
        unsigned y1 = pkbits(st[k][8 * sl + 6], st[k][8 * sl + 7]);
        asm("v_permlane32_swap_b32 %0, %1" : "+v"(x0), "+v"(y0));
        asm("v_permlane32_swap_b32 %0, %1" : "+v"(x1), "+v"(y1));
        union { unsigned u[4]; f16x8 v; } pu;
        pu.u[0] = x0; pu.u[1] = x1; pu.u[2] = y0; pu.u[3] = y1;
        pa[2 * k + sl] = pu.v;
      }
    }

    // ---- PV + den: acc += pa[s] x V^T rows; dacc += pa[s] x 1 ----
    __builtin_amdgcn_s_setprio(1);
    #pragma unroll
    for (int s = 0; s < 8; ++s) {
      f16x8 vf0 = *(const f16x8*)&Vl[buf][q32 * 128 + vco[s]];
      f16x8 vf1 = *(const f16x8*)&Vl[buf][(32 + q32) * 128 + vco[s]];
      acc0 = mfma32(pa[s], vf0, acc0);
      acc1 = mfma32(pa[s], vf1, acc1);
      dacc = mfma32(pa[s], onesf, dacc);
    }
    __builtin_amdgcn_s_setprio(0);
  };

  // ---- 2-phase pipeline: stage t+1 early, ONE barrier per 128-key tile ----
  stage(0, 0);
  __syncthreads();                      // drains vmcnt -> tile 0 visible
  #pragma unroll 1
  for (int t = 0; t < NT128; t += 2) {
    stage(1, t + 1);                    // in flight during compute
    compute(0);
    __syncthreads();                    // drain + WAR fence
    if (t + 2 < NT128) stage(0, t + 2);
    compute(1);
    __syncthreads();
  }

  // ---- epilogue: den in C-layout -> shfl-free; coalesced f32 stores ----
  #pragma unroll
  for (int r = 0; r < 16; ++r) {
    const int crow = (r & 3) + 8 * (r >> 2) + 4 * hi;
    float rden = 1.0f / dacc[r];
    float* po = out + (size_t)(b * SEQ + qb + crow) * DIMS + hoff;
    po[q32] = acc0[r] * rden;
    po[32 + q32] = acc1[r] * rden;
  }
}

extern "C" void kernel_launch(void* const* d_in, const int* in_sizes, int n_in,
                              void* d_out, int out_size, void* d_ws, size_t ws_size,
                              hipStream_t stream) {
  const float* q = (const float*)d_in[0];
  const float* k = (const float*)d_in[1];
  const float* v = (const float*)d_in[2];
  float* out = (float*)d_out;

  // workspace: Khf | Vt, each 2*16*2048*64 fp16 = 8 MiB
  const size_t tsz = (size_t)2 * HEADS * SEQ * DEPTH;  // elements
  _Float16* khf = (_Float16*)d_ws;
  _Float16* vtp = khf + tsz;

  prep_kv<<<4096, 256, 0, stream>>>(k, v, khf, vtp);
  attn_fwd<<<512, 256, 0, stream>>>(q, khf, vtp, out);
}